// Round 2
// baseline (2285.864 us; speedup 1.0000x reference)
//
#include <hip/hip_runtime.h>
#include <stdint.h>

// ---------------------------------------------------------------------------
// Discriminator_RNN_Utt: 2-layer GRU (B=1024,T=63,F=257,H=512) + MLP heads.
// bf16 MFMA, fp32 accumulation + gate math. Workspace kept ~16 MB.
// Pipeline: phase p runs XG(t=p) | L0(t=p-1) | L1(t=p-2), 65 phases.
// ---------------------------------------------------------------------------

typedef __bf16 bf16x8 __attribute__((ext_vector_type(8)));
typedef float f32x4 __attribute__((ext_vector_type(4)));

__device__ __forceinline__ unsigned short f2bf(float f) {
  unsigned int u = __float_as_uint(f);
  u += 0x7fffu + ((u >> 16) & 1u);   // RNE
  return (unsigned short)(u >> 16);
}
__device__ __forceinline__ float bf2f(unsigned short s) {
  return __uint_as_float(((unsigned int)s) << 16);
}
__device__ __forceinline__ float sigm(float x) { return 1.f / (1.f + __expf(-x)); }
__device__ __forceinline__ float tanh_(float x) { return 1.f - 2.f / (1.f + __expf(2.f * x)); }

__device__ __forceinline__ bf16x8 ld_frag(const unsigned short* p) {
  uint4 u = *(const uint4*)p;
  return __builtin_bit_cast(bf16x8, u);
}

// ------------------------- fp32 -> bf16 (+row pad) -------------------------
__global__ void conv_pad_kernel(const float* __restrict__ src,
                                unsigned short* __restrict__ dst,
                                int rows, int sk, int dk) {
  int idx = blockIdx.x * 256 + threadIdx.x;  // one per 8 outputs
  int cpr = dk >> 3;
  if (idx >= rows * cpr) return;
  int row = idx / cpr;
  int c0 = (idx - row * cpr) << 3;
  const float* s = src + (size_t)row * sk;
  union { unsigned short v[8]; uint4 u; } t;
#pragma unroll
  for (int j = 0; j < 8; ++j) {
    int c = c0 + j;
    t.v[j] = (c < sk) ? f2bf(s[c]) : (unsigned short)0;
  }
  *(uint4*)(dst + (size_t)row * dk + c0) = t.u;
}

// ---------------- zero a contiguous region (g0, q0, x3) --------------------
__global__ void zero_ws_kernel(uint4* __restrict__ a, int n) {
  int i = blockIdx.x * 256 + threadIdx.x;
  uint4 z = {0u, 0u, 0u, 0u};
  if (i < n) a[i] = z;
}

// --------------------- fused GRU phase (pipelined) -------------------------
// blocks 0..127  : layer0 step t=p-1 (active 1<=p<=63)  Btile=64
// blocks 128..383: layer1 step t=p-2 (active p>=2)      Btile=32, +x3 accum
// blocks 384..479: xg(t=p) = x[:,p,:] @ w_ih0^T + b_ih0 (active p<=62)
__global__ __launch_bounds__(256) void gru_phase_kernel(
    const float* __restrict__ x,
    const unsigned short* __restrict__ wih0b, const float* __restrict__ bih0,
    unsigned short* __restrict__ xgcur,        // xgbuf[p&1]     (XG out)
    const unsigned short* __restrict__ xgprev, // xgbuf[(p+1)&1] (L0 in)
    const unsigned short* __restrict__ gA,     // gbuf[(p+1)&1]  (L0 h_prev, L1 gcur)
    unsigned short* __restrict__ gB,           // gbuf[p&1]      (L0 h_new)
    const unsigned short* __restrict__ qA,     // qbuf[p&1]      (L1 h_prev)
    unsigned short* __restrict__ qB,           // qbuf[(p+1)&1]  (L1 h_new)
    const unsigned short* __restrict__ whh0, const float* __restrict__ bhh0,
    const unsigned short* __restrict__ wih1, const unsigned short* __restrict__ whh1,
    const float* __restrict__ bih1, const float* __restrict__ bhh1,
    const float* __restrict__ dnnw, float* __restrict__ x3, int p) {
  __shared__ __align__(16) unsigned short sm[32768];  // 64KB
  const int tid = threadIdx.x;
  const int lane = tid & 63, w = tid >> 6;
  const int lm = lane & 15, lk = lane >> 4;
  const int bid = blockIdx.x;

  if (bid < 128) {  // ---------------- layer 0, t = p-1 ----------------
    if (p < 1 || p > 63) return;
    const int mt = bid & 7, b0 = (bid >> 3) * 64;
#pragma unroll
    for (int s = 0; s < 16; ++s) {  // stage gA[b0..b0+63][0..511], XOR swizzle
      int c = tid + (s << 8);
      int row = c >> 6, ch = c & 63, sw = ch ^ (row & 7);
      *(uint4*)&sm[row * 512 + sw * 8] =
          *(const uint4*)(gA + ((size_t)(b0 + row) << 9) + ch * 8);
    }
    __syncthreads();
    f32x4 acc[4][3];
#pragma unroll
    for (int i = 0; i < 4; ++i)
#pragma unroll
      for (int g = 0; g < 3; ++g) acc[i][g] = {0.f, 0.f, 0.f, 0.f};
    const int muB = mt * 64 + w * 16;
    for (int kk = 0; kk < 16; ++kk) {
      bf16x8 a[4];
#pragma unroll
      for (int mf = 0; mf < 4; ++mf) {
        int row = mf * 16 + lm;
        int sw = (kk * 4 + lk) ^ (row & 7);
        a[mf] = ld_frag(&sm[row * 512 + sw * 8]);
      }
#pragma unroll
      for (int g = 0; g < 3; ++g) {
        bf16x8 bw = ld_frag(whh0 + ((size_t)(g * 512 + muB + lm) << 9) + kk * 32 + lk * 8);
#pragma unroll
        for (int mf = 0; mf < 4; ++mf)
          acc[mf][g] = __builtin_amdgcn_mfma_f32_16x16x32_bf16(a[mf], bw, acc[mf][g], 0, 0, 0);
      }
    }
    const int mu = muB + lm;
    const float br = bhh0[mu], bz = bhh0[512 + mu], bn = bhh0[1024 + mu];
#pragma unroll
    for (int mf = 0; mf < 4; ++mf)
#pragma unroll
      for (int r = 0; r < 4; ++r) {
        int brl = mf * 16 + lk * 4 + r;
        int brow = b0 + brl;
        const unsigned short* xr = xgprev + (size_t)brow * 1536;
        float rr = sigm(bf2f(xr[mu]) + acc[mf][0][r] + br);
        float zz = sigm(bf2f(xr[512 + mu]) + acc[mf][1][r] + bz);
        float nn = tanh_(bf2f(xr[1024 + mu]) + rr * (acc[mf][2][r] + bn));
        int chs = (mu >> 3) ^ (brl & 7);
        float hp = bf2f(sm[brl * 512 + chs * 8 + (mu & 7)]);
        gB[((size_t)brow << 9) + mu] = f2bf(nn - nn * zz + zz * hp);
      }
  } else if (bid < 384) {  // ---------------- layer 1, t = p-2 ----------------
    if (p < 2) return;
    const int lb = bid - 128;
    const int mt = lb & 7, b0 = (lb >> 3) * 32;
    const int t = p - 2;
    unsigned short* smA = sm;            // gcur  [32][512]
    unsigned short* smB = sm + 16384;    // qprev [32][512]
#pragma unroll
    for (int s = 0; s < 8; ++s) {
      int c = tid + (s << 8);
      int row = c >> 6, ch = c & 63, sw = ch ^ (row & 7);
      size_t go = ((size_t)(b0 + row) << 9) + ch * 8;
      *(uint4*)&smA[row * 512 + sw * 8] = *(const uint4*)(gA + go);
      *(uint4*)&smB[row * 512 + sw * 8] = *(const uint4*)(qA + go);
    }
    __syncthreads();
    f32x4 aI[2][3], aH[2][3];
#pragma unroll
    for (int i = 0; i < 2; ++i)
#pragma unroll
      for (int g = 0; g < 3; ++g) { aI[i][g] = {0.f, 0.f, 0.f, 0.f}; aH[i][g] = {0.f, 0.f, 0.f, 0.f}; }
    const int muB = mt * 64 + w * 16;
    for (int kk = 0; kk < 16; ++kk) {
      bf16x8 a0[2], a1[2];
#pragma unroll
      for (int mf = 0; mf < 2; ++mf) {
        int row = mf * 16 + lm;
        int sw = (kk * 4 + lk) ^ (row & 7);
        a0[mf] = ld_frag(&smA[row * 512 + sw * 8]);
        a1[mf] = ld_frag(&smB[row * 512 + sw * 8]);
      }
#pragma unroll
      for (int g = 0; g < 3; ++g) {
        size_t wro = ((size_t)(g * 512 + muB + lm) << 9) + kk * 32 + lk * 8;
        bf16x8 bi = ld_frag(wih1 + wro);
#pragma unroll
        for (int mf = 0; mf < 2; ++mf)
          aI[mf][g] = __builtin_amdgcn_mfma_f32_16x16x32_bf16(a0[mf], bi, aI[mf][g], 0, 0, 0);
        bf16x8 bh = ld_frag(whh1 + wro);
#pragma unroll
        for (int mf = 0; mf < 2; ++mf)
          aH[mf][g] = __builtin_amdgcn_mfma_f32_16x16x32_bf16(a1[mf], bh, aH[mf][g], 0, 0, 0);
      }
    }
    const int mu = muB + lm;
    const float bir = bih1[mu], biz = bih1[512 + mu], bin = bih1[1024 + mu];
    const float bhr = bhh1[mu], bhz = bhh1[512 + mu], bhn = bhh1[1024 + mu];
    const float dw = dnnw[mu];
    float red[2][4];
#pragma unroll
    for (int mf = 0; mf < 2; ++mf)
#pragma unroll
      for (int r = 0; r < 4; ++r) {
        int brl = mf * 16 + lk * 4 + r;
        int brow = b0 + brl;
        float rr = sigm(aI[mf][0][r] + bir + aH[mf][0][r] + bhr);
        float zz = sigm(aI[mf][1][r] + biz + aH[mf][1][r] + bhz);
        float nn = tanh_(aI[mf][2][r] + bin + rr * (aH[mf][2][r] + bhn));
        int chs = (mu >> 3) ^ (brl & 7);
        float hp = bf2f(smB[brl * 512 + chs * 8 + (mu & 7)]);
        float hv = nn - nn * zz + zz * hp;
        qB[((size_t)brow << 9) + mu] = f2bf(hv);
        float v = hv * dw;  // dnn-head partial: reduce over lm group (16 lanes)
        v += __shfl_xor(v, 1); v += __shfl_xor(v, 2);
        v += __shfl_xor(v, 4); v += __shfl_xor(v, 8);
        red[mf][r] = v;
      }
    __syncthreads();                 // smA/smB dead; reuse as fp32 partials
    float* part = (float*)sm;
    if (tid < 32) part[tid] = 0.f;
    __syncthreads();
    if (lm == 0) {
#pragma unroll
      for (int mf = 0; mf < 2; ++mf)
#pragma unroll
        for (int r = 0; r < 4; ++r)
          atomicAdd(&part[mf * 16 + lk * 4 + r], red[mf][r]);
    }
    __syncthreads();
    if (tid < 32) atomicAdd(&x3[(size_t)(b0 + tid) * 63 + t], part[tid]);
  } else {  // ---------------- XG: xg(t=p) = x_t @ w_ih0^T + b_ih0 ----------------
    if (p > 62) return;
    const int t = p;
    const int lb = bid - 384;
    const int m0 = (lb / 12) * 128, n0 = (lb % 12) * 128;
    unsigned short* As = sm;                // [128][40]
    unsigned short* Bs = sm + 128 * 40;     // [128][40]
    const int wm = w >> 1, wn = w & 1;
    f32x4 acc[4][4];
#pragma unroll
    for (int i = 0; i < 4; ++i)
#pragma unroll
      for (int j = 0; j < 4; ++j) acc[i][j] = {0.f, 0.f, 0.f, 0.f};
    for (int kk = 0; kk < 288; kk += 32) {
#pragma unroll
      for (int s = 0; s < 2; ++s) {
        int c = tid + (s << 8);
        int row = c >> 2, c8 = (c & 3) << 3;
        const float* xr = x + ((size_t)(m0 + row) * 63 + t) * 257;
        union { unsigned short v[8]; uint4 u; } tA;
#pragma unroll
        for (int j = 0; j < 8; ++j) {
          int col = kk + c8 + j;
          tA.v[j] = (col < 257) ? f2bf(xr[col]) : (unsigned short)0;
        }
        *(uint4*)&As[row * 40 + c8] = tA.u;
        *(uint4*)&Bs[row * 40 + c8] =
            *(const uint4*)(wih0b + (size_t)(n0 + row) * 288 + kk + c8);
      }
      __syncthreads();
      bf16x8 a[4], b[4];
#pragma unroll
      for (int i = 0; i < 4; ++i)
        a[i] = ld_frag(&As[(wm * 64 + i * 16 + lm) * 40 + lk * 8]);
#pragma unroll
      for (int j = 0; j < 4; ++j)
        b[j] = ld_frag(&Bs[(wn * 64 + j * 16 + lm) * 40 + lk * 8]);
#pragma unroll
      for (int i = 0; i < 4; ++i)
#pragma unroll
        for (int j = 0; j < 4; ++j)
          acc[i][j] = __builtin_amdgcn_mfma_f32_16x16x32_bf16(a[i], b[j], acc[i][j], 0, 0, 0);
      __syncthreads();
    }
#pragma unroll
    for (int i = 0; i < 4; ++i)
#pragma unroll
      for (int j = 0; j < 4; ++j) {
        int n = n0 + wn * 64 + j * 16 + lm;
        float bv = bih0[n];
#pragma unroll
        for (int r = 0; r < 4; ++r) {
          int m = m0 + wm * 64 + i * 16 + lk * 4 + r;
          xgcur[(size_t)m * 1536 + n] = f2bf(acc[i][j][r] + bv);
        }
      }
  }
}

// ------------------------------- heads -------------------------------------
__global__ __launch_bounds__(64) void head_kernel(
    const float* __restrict__ x3, const float* __restrict__ dnn_b,
    const float* __restrict__ w1, const float* __restrict__ b1,
    const float* __restrict__ w2, const float* __restrict__ b2,
    const float* __restrict__ w3, const float* __restrict__ b3,
    float* __restrict__ out) {
  __shared__ float x3s[63], x4[32], x5[16];
  const int b = blockIdx.x, l = threadIdx.x;
  if (l < 63) x3s[l] = x3[(size_t)b * 63 + l] + dnn_b[0];
  __syncthreads();
  if (l < 32) {
    float s = b1[l];
    for (int t = 0; t < 63; ++t) s += x3s[t] * w1[l * 63 + t];
    x4[l] = s;
  }
  __syncthreads();
  if (l < 16) {
    float s = b2[l];
#pragma unroll
    for (int j = 0; j < 32; ++j) s += x4[j] * w2[l * 32 + j];
    x5[l] = s;
  }
  __syncthreads();
  if (l == 0) {
    float s = b3[0];
#pragma unroll
    for (int j = 0; j < 16; ++j) s += x5[j] * w3[j];
    out[b] = s;
  }
}

// ---------------------------------------------------------------------------
extern "C" void kernel_launch(void* const* d_in, const int* in_sizes, int n_in,
                              void* d_out, int out_size, void* d_ws, size_t ws_size,
                              hipStream_t stream) {
  const float* x    = (const float*)d_in[0];
  const float* wih0 = (const float*)d_in[1];
  const float* whh0 = (const float*)d_in[2];
  const float* bih0 = (const float*)d_in[3];
  const float* bhh0 = (const float*)d_in[4];
  const float* wih1 = (const float*)d_in[5];
  const float* whh1 = (const float*)d_in[6];
  const float* bih1 = (const float*)d_in[7];
  const float* bhh1 = (const float*)d_in[8];
  const float* dnnw = (const float*)d_in[9];
  const float* dnnb = (const float*)d_in[10];
  const float* w1   = (const float*)d_in[11];
  const float* b1   = (const float*)d_in[12];
  const float* w2   = (const float*)d_in[13];
  const float* b2   = (const float*)d_in[14];
  const float* w3   = (const float*)d_in[15];
  const float* b3   = (const float*)d_in[16];
  float* out = (float*)d_out;

  char* p = (char*)d_ws;
  auto alloc = [&](size_t bytes) {
    char* r = p;
    p += (bytes + 255) & ~(size_t)255;
    return r;
  };
  // total ~16.3 MB
  unsigned short* xgbuf[2];
  xgbuf[0] = (unsigned short*)alloc((size_t)1024 * 1536 * 2);
  xgbuf[1] = (unsigned short*)alloc((size_t)1024 * 1536 * 2);
  unsigned short* wih0b = (unsigned short*)alloc((size_t)1536 * 288 * 2);
  unsigned short* whh0b = (unsigned short*)alloc((size_t)1536 * 512 * 2);
  unsigned short* wih1b = (unsigned short*)alloc((size_t)1536 * 512 * 2);
  unsigned short* whh1b = (unsigned short*)alloc((size_t)1536 * 512 * 2);
  unsigned short* gbuf[2], *qbuf[2];
  gbuf[0] = (unsigned short*)alloc((size_t)1024 * 512 * 2);   // contiguous with
  qbuf[0] = (unsigned short*)alloc((size_t)1024 * 512 * 2);   // qbuf[0], x3:
  float* x3 = (float*)alloc((size_t)1024 * 63 * 4);           // one zero pass
  gbuf[1] = (unsigned short*)alloc((size_t)1024 * 512 * 2);
  qbuf[1] = (unsigned short*)alloc((size_t)1024 * 512 * 2);
  (void)ws_size; (void)in_sizes; (void)n_in; (void)out_size;

  // zero g0 | q0 | x3 (contiguous, 2355200 B = 147200 uint4)
  zero_ws_kernel<<<576, 256, 0, stream>>>((uint4*)gbuf[0], 147200);

  // weights -> bf16 (w_ih0 padded 257->288)
  conv_pad_kernel<<<216, 256, 0, stream>>>(wih0, wih0b, 1536, 257, 288);
  conv_pad_kernel<<<384, 256, 0, stream>>>(whh0, whh0b, 1536, 512, 512);
  conv_pad_kernel<<<384, 256, 0, stream>>>(wih1, wih1b, 1536, 512, 512);
  conv_pad_kernel<<<384, 256, 0, stream>>>(whh1, whh1b, 1536, 512, 512);

  // pipelined recurrence: phase p = XG(t=p) | L0(t=p-1) | L1(t=p-2)
  for (int ph = 0; ph <= 64; ++ph) {
    gru_phase_kernel<<<480, 256, 0, stream>>>(
        x, wih0b, bih0,
        xgbuf[ph & 1], xgbuf[(ph + 1) & 1],
        gbuf[(ph + 1) & 1], gbuf[ph & 1],
        qbuf[ph & 1], qbuf[(ph + 1) & 1],
        whh0b, bhh0, wih1b, whh1b, bih1, bhh1,
        dnnw, x3, ph);
  }

  // heads -> out [1024]
  head_kernel<<<1024, 64, 0, stream>>>(x3, dnnb, w1, b1, w2, b2, w3, b3, out);
}